// Round 1
// baseline (150.628 us; speedup 1.0000x reference)
//
#include <hip/hip_runtime.h>
#include <stdint.h>

#define NV 8192   // vision rows
#define MT 8192   // text rows
#define DD 128    // feature dim
#define KB 768    // BERT dim

typedef __attribute__((ext_vector_type(8))) short short8;
typedef __attribute__((ext_vector_type(4))) float f32x4;

__device__ __forceinline__ ushort f2bf(float f) {
  uint32_t u = __float_as_uint(f);
  u += 0x7FFF + ((u >> 16) & 1);   // round-to-nearest-even
  return (ushort)(u >> 16);
}

// ---------------- Kernel 1: vision row-normalize -> bf16 ----------------
// 256 threads, 16 rows/block, 16 lanes/row (8 floats each)
__global__ __launch_bounds__(256) void k_visnorm(const float* __restrict__ vis,
                                                 ushort* __restrict__ vn) {
  const int tx = threadIdx.x & 15;
  const int r  = blockIdx.x * 16 + (threadIdx.x >> 4);
  const float* p = vis + (size_t)r * DD + tx * 8;
  float4 a = *(const float4*)p;
  float4 b = *(const float4*)(p + 4);
  float s = a.x*a.x + a.y*a.y + a.z*a.z + a.w*a.w
          + b.x*b.x + b.y*b.y + b.z*b.z + b.w*b.w;
  s += __shfl_xor(s, 1, 16);
  s += __shfl_xor(s, 2, 16);
  s += __shfl_xor(s, 4, 16);
  s += __shfl_xor(s, 8, 16);
  const float inv = 1.0f / fmaxf(sqrtf(s), 1e-8f);
  union { ushort u[8]; uint4 v; } o;
  o.u[0] = f2bf(a.x * inv); o.u[1] = f2bf(a.y * inv);
  o.u[2] = f2bf(a.z * inv); o.u[3] = f2bf(a.w * inv);
  o.u[4] = f2bf(b.x * inv); o.u[5] = f2bf(b.y * inv);
  o.u[6] = f2bf(b.z * inv); o.u[7] = f2bf(b.w * inv);
  *(uint4*)(vn + (size_t)r * DD + tx * 8) = o.v;
}

// ---------------- Kernel 2: text projection (f32) + bias + normalize -> bf16
// Block: 512 threads, 32 text rows, all 128 output dims.
// thread (ty=tid>>4 -> row, tx=tid&15 -> 8 dims at d0=tx*8), acc[8] f32.
// K loop in chunks of 64, W chunk staged transposed in LDS.
__global__ __launch_bounds__(512) void k_proj(const float* __restrict__ txt,
                                              const float* __restrict__ w,
                                              const float* __restrict__ bias,
                                              ushort* __restrict__ tn) {
  __shared__ float wT[64][132];  // [kk][d], pad 132 to break power-of-2
  __shared__ float tt[32][68];   // [r][kk]
  const int tid = threadIdx.x;
  const int tx = tid & 15;
  const int ty = tid >> 4;       // 0..31
  const int rb = blockIdx.x * 32;
  const int row = rb + ty;
  const int d0 = tx * 8;

  float acc[8] = {0.f, 0.f, 0.f, 0.f, 0.f, 0.f, 0.f, 0.f};

  for (int k0 = 0; k0 < KB; k0 += 64) {
    // stage W chunk transposed: 128 d x 64 k = 2048 float4 slots
#pragma unroll
    for (int i = 0; i < 4; ++i) {
      int li = tid + i * 512;
      int d  = li >> 4;
      int k4 = (li & 15) << 2;
      float4 v = *(const float4*)(w + (size_t)d * KB + k0 + k4);
      wT[k4 + 0][d] = v.x;
      wT[k4 + 1][d] = v.y;
      wT[k4 + 2][d] = v.z;
      wT[k4 + 3][d] = v.w;
    }
    // stage text chunk: 32 r x 64 k = 512 float4 slots
    {
      int r  = tid >> 4;
      int k4 = (tid & 15) << 2;
      *(float4*)&tt[r][k4] = *(const float4*)(txt + (size_t)(rb + r) * KB + k0 + k4);
    }
    __syncthreads();

#pragma unroll 8
    for (int kk = 0; kk < 64; ++kk) {
      float t0 = tt[ty][kk];
      float4 w0 = *(const float4*)&wT[kk][d0];
      float4 w1 = *(const float4*)&wT[kk][d0 + 4];
      acc[0] = fmaf(t0, w0.x, acc[0]);
      acc[1] = fmaf(t0, w0.y, acc[1]);
      acc[2] = fmaf(t0, w0.z, acc[2]);
      acc[3] = fmaf(t0, w0.w, acc[3]);
      acc[4] = fmaf(t0, w1.x, acc[4]);
      acc[5] = fmaf(t0, w1.y, acc[5]);
      acc[6] = fmaf(t0, w1.z, acc[6]);
      acc[7] = fmaf(t0, w1.w, acc[7]);
    }
    __syncthreads();
  }

  // bias
  float4 b0 = *(const float4*)(bias + d0);
  float4 b1 = *(const float4*)(bias + d0 + 4);
  acc[0] += b0.x; acc[1] += b0.y; acc[2] += b0.z; acc[3] += b0.w;
  acc[4] += b1.x; acc[5] += b1.y; acc[6] += b1.z; acc[7] += b1.w;

  // row norm across the 16 lanes holding this row
  float s = acc[0]*acc[0] + acc[1]*acc[1] + acc[2]*acc[2] + acc[3]*acc[3]
          + acc[4]*acc[4] + acc[5]*acc[5] + acc[6]*acc[6] + acc[7]*acc[7];
  s += __shfl_xor(s, 1, 16);
  s += __shfl_xor(s, 2, 16);
  s += __shfl_xor(s, 4, 16);
  s += __shfl_xor(s, 8, 16);
  const float inv = 1.0f / fmaxf(sqrtf(s), 1e-8f);

  union { ushort u[8]; uint4 v; } o;
#pragma unroll
  for (int i = 0; i < 8; ++i) o.u[i] = f2bf(acc[i] * inv);
  *(uint4*)(tn + (size_t)row * DD + d0) = o.v;
}

// ---------------- Kernel 3: similarity GEMM (bf16 MFMA, f32 out) ---------
// grid (64,64): block tile 128x128; 4 waves in 2x2, each wave 64x64.
// K=128 total: 4 steps of 16x16x32 MFMA. Fragments loaded straight from
// global (vn+tn = 4MB, L2-resident); kernel is output-write-bound.
__global__ __launch_bounds__(256, 3) void k_sim(const ushort* __restrict__ vn,
                                                const ushort* __restrict__ tn,
                                                float* __restrict__ out) {
  const int lane = threadIdx.x & 63;
  const int wave = threadIdx.x >> 6;
  const int row0 = blockIdx.y * 128 + (wave >> 1) * 64;
  const int col0 = blockIdx.x * 128 + (wave & 1) * 64;
  const int lrow = lane & 15;
  const int koff = (lane >> 4) * 8;

  const ushort* ap = vn + (size_t)(row0 + lrow) * DD + koff;
  const ushort* bp = tn + (size_t)(col0 + lrow) * DD + koff;

  f32x4 acc[4][4] = {};

#pragma unroll
  for (int ks = 0; ks < 4; ++ks) {
    short8 a[4], b[4];
#pragma unroll
    for (int m = 0; m < 4; ++m)
      a[m] = *(const short8*)(ap + (size_t)m * 16 * DD + ks * 32);
#pragma unroll
    for (int n = 0; n < 4; ++n)
      b[n] = *(const short8*)(bp + (size_t)n * 16 * DD + ks * 32);
#pragma unroll
    for (int m = 0; m < 4; ++m)
#pragma unroll
      for (int n = 0; n < 4; ++n)
        acc[m][n] = __builtin_amdgcn_mfma_f32_16x16x32_bf16(a[m], b[n], acc[m][n], 0, 0, 0);
  }

  // C/D layout (m89-verified): col = lane&15, row = (lane>>4)*4 + reg
  const int orow = (lane >> 4) * 4;
  const int ocol = lane & 15;
  float* op = out + (size_t)(row0 + orow) * MT + col0 + ocol;
#pragma unroll
  for (int m = 0; m < 4; ++m)
#pragma unroll
    for (int n = 0; n < 4; ++n)
#pragma unroll
      for (int j = 0; j < 4; ++j)
        op[(size_t)(m * 16 + j) * MT + n * 16] = acc[m][n][j];
}

extern "C" void kernel_launch(void* const* d_in, const int* in_sizes, int n_in,
                              void* d_out, int out_size, void* d_ws, size_t ws_size,
                              hipStream_t stream) {
  (void)in_sizes; (void)n_in; (void)out_size; (void)ws_size;
  const float* vis  = (const float*)d_in[0];  // [8192,128]
  const float* txt  = (const float*)d_in[1];  // [8192,768]
  const float* w    = (const float*)d_in[2];  // [128,768]
  const float* bias = (const float*)d_in[3];  // [128]
  float* out = (float*)d_out;                 // [8192,8192]

  ushort* vn = (ushort*)d_ws;                      // 8192*128 bf16 = 2 MB
  ushort* tn = vn + (size_t)NV * DD;               // 2 MB

  k_visnorm<<<NV / 16, 256, 0, stream>>>(vis, vn);
  k_proj<<<MT / 32, 512, 0, stream>>>(txt, w, bias, tn);
  k_sim<<<dim3(MT / 128, NV / 128), 256, 0, stream>>>(vn, tn, out);
}

// Round 2
// 121.178 us; speedup vs baseline: 1.2430x; 1.2430x over previous
//
#include <hip/hip_runtime.h>
#include <stdint.h>

#define NV 8192   // vision rows
#define MT 8192   // text rows
#define DD 128    // feature dim
#define KB 768    // BERT dim

typedef __attribute__((ext_vector_type(8))) short short8;
typedef __attribute__((ext_vector_type(4))) float f32x4;

__device__ __forceinline__ ushort f2bf(float f) {
  uint32_t u = __float_as_uint(f);
  u += 0x7FFF + ((u >> 16) & 1);   // round-to-nearest-even
  return (ushort)(u >> 16);
}

// ---------------- Kernel 1: vision row-normalize -> bf16 ----------------
// 256 threads, 16 rows/block, 16 lanes/row (8 floats each)
__global__ __launch_bounds__(256) void k_visnorm(const float* __restrict__ vis,
                                                 ushort* __restrict__ vn) {
  const int tx = threadIdx.x & 15;
  const int r  = blockIdx.x * 16 + (threadIdx.x >> 4);
  const float* p = vis + (size_t)r * DD + tx * 8;
  float4 a = *(const float4*)p;
  float4 b = *(const float4*)(p + 4);
  float s = a.x*a.x + a.y*a.y + a.z*a.z + a.w*a.w
          + b.x*b.x + b.y*b.y + b.z*b.z + b.w*b.w;
  s += __shfl_xor(s, 1, 16);
  s += __shfl_xor(s, 2, 16);
  s += __shfl_xor(s, 4, 16);
  s += __shfl_xor(s, 8, 16);
  const float inv = 1.0f / fmaxf(sqrtf(s), 1e-8f);
  union { ushort u[8]; uint4 v; } o;
  o.u[0] = f2bf(a.x * inv); o.u[1] = f2bf(a.y * inv);
  o.u[2] = f2bf(a.z * inv); o.u[3] = f2bf(a.w * inv);
  o.u[4] = f2bf(b.x * inv); o.u[5] = f2bf(b.y * inv);
  o.u[6] = f2bf(b.z * inv); o.u[7] = f2bf(b.w * inv);
  *(uint4*)(vn + (size_t)r * DD + tx * 8) = o.v;
}

// ---------------- Kernel 2: f32 -> bf16 bulk convert (8 elems/thread) ----
__global__ __launch_bounds__(256) void k_cvt(const float* __restrict__ src,
                                             ushort* __restrict__ dst) {
  const size_t i = ((size_t)blockIdx.x * 256 + threadIdx.x) * 8;
  float4 a = *(const float4*)(src + i);
  float4 b = *(const float4*)(src + i + 4);
  union { ushort u[8]; uint4 v; } o;
  o.u[0] = f2bf(a.x); o.u[1] = f2bf(a.y); o.u[2] = f2bf(a.z); o.u[3] = f2bf(a.w);
  o.u[4] = f2bf(b.x); o.u[5] = f2bf(b.y); o.u[6] = f2bf(b.z); o.u[7] = f2bf(b.w);
  *(uint4*)(dst + i) = o.v;
}

// ---------------- Kernel 3: projection GEMM (bf16 MFMA -> f32 pre-norm) --
// 1 wave/block, wave computes 64 rows x 64 dims; grid (2, 128).
// A = tb rows (M=8192, K=768), B = wb rows (N=128 dims, K=768), both
// K-contiguous row-major (B^T form). 24 K-steps of 16x16x32.
__global__ __launch_bounds__(64) void k_projmfma(const ushort* __restrict__ tb,
                                                 const ushort* __restrict__ wb,
                                                 float* __restrict__ tf) {
  const int lane = threadIdx.x;
  const int row0 = blockIdx.y * 64;
  const int col0 = blockIdx.x * 64;
  const int lrow = lane & 15;
  const int koff = (lane >> 4) * 8;

  const ushort* ap = tb + (size_t)(row0 + lrow) * KB + koff;
  const ushort* bp = wb + (size_t)(col0 + lrow) * KB + koff;

  f32x4 acc[4][4] = {};

#pragma unroll 4
  for (int ks = 0; ks < KB / 32; ++ks) {
    short8 a[4], b[4];
#pragma unroll
    for (int m = 0; m < 4; ++m)
      a[m] = *(const short8*)(ap + (size_t)m * 16 * KB + ks * 32);
#pragma unroll
    for (int n = 0; n < 4; ++n)
      b[n] = *(const short8*)(bp + (size_t)n * 16 * KB + ks * 32);
#pragma unroll
    for (int m = 0; m < 4; ++m)
#pragma unroll
      for (int n = 0; n < 4; ++n)
        acc[m][n] = __builtin_amdgcn_mfma_f32_16x16x32_bf16(a[m], b[n], acc[m][n], 0, 0, 0);
  }

  const int orow = (lane >> 4) * 4;
  const int ocol = lane & 15;
  float* op = tf + (size_t)(row0 + orow) * DD + col0 + ocol;
#pragma unroll
  for (int m = 0; m < 4; ++m)
#pragma unroll
    for (int n = 0; n < 4; ++n)
#pragma unroll
      for (int j = 0; j < 4; ++j)
        op[(size_t)(m * 16 + j) * DD + n * 16] = acc[m][n][j];
}

// ---------------- Kernel 4: bias + row-normalize -> bf16 -----------------
// 256 threads, 16 rows/block, 16 lanes/row (8 f32 each)
__global__ __launch_bounds__(256) void k_tnorm(const float* __restrict__ tf,
                                               const float* __restrict__ bias,
                                               ushort* __restrict__ tn) {
  const int tx = threadIdx.x & 15;
  const int r  = blockIdx.x * 16 + (threadIdx.x >> 4);
  const int d0 = tx * 8;
  const float* p = tf + (size_t)r * DD + d0;
  float4 a = *(const float4*)p;
  float4 b = *(const float4*)(p + 4);
  float4 ba = *(const float4*)(bias + d0);
  float4 bb = *(const float4*)(bias + d0 + 4);
  a.x += ba.x; a.y += ba.y; a.z += ba.z; a.w += ba.w;
  b.x += bb.x; b.y += bb.y; b.z += bb.z; b.w += bb.w;
  float s = a.x*a.x + a.y*a.y + a.z*a.z + a.w*a.w
          + b.x*b.x + b.y*b.y + b.z*b.z + b.w*b.w;
  s += __shfl_xor(s, 1, 16);
  s += __shfl_xor(s, 2, 16);
  s += __shfl_xor(s, 4, 16);
  s += __shfl_xor(s, 8, 16);
  const float inv = 1.0f / fmaxf(sqrtf(s), 1e-8f);
  union { ushort u[8]; uint4 v; } o;
  o.u[0] = f2bf(a.x * inv); o.u[1] = f2bf(a.y * inv);
  o.u[2] = f2bf(a.z * inv); o.u[3] = f2bf(a.w * inv);
  o.u[4] = f2bf(b.x * inv); o.u[5] = f2bf(b.y * inv);
  o.u[6] = f2bf(b.z * inv); o.u[7] = f2bf(b.w * inv);
  *(uint4*)(tn + (size_t)r * DD + d0) = o.v;
}

// ---------------- Kernel 5: similarity GEMM (bf16 MFMA, f32 out) ---------
// grid (64,64): block tile 128x128; 4 waves in 2x2, each wave 64x64.
// K=128 total: 4 steps of 16x16x32 MFMA. Fragments loaded straight from
// global (vn+tn = 4MB, L2-resident); kernel is output-write-bound.
__global__ __launch_bounds__(256, 3) void k_sim(const ushort* __restrict__ vn,
                                                const ushort* __restrict__ tn,
                                                float* __restrict__ out) {
  const int lane = threadIdx.x & 63;
  const int wave = threadIdx.x >> 6;
  const int row0 = blockIdx.y * 128 + (wave >> 1) * 64;
  const int col0 = blockIdx.x * 128 + (wave & 1) * 64;
  const int lrow = lane & 15;
  const int koff = (lane >> 4) * 8;

  const ushort* ap = vn + (size_t)(row0 + lrow) * DD + koff;
  const ushort* bp = tn + (size_t)(col0 + lrow) * DD + koff;

  f32x4 acc[4][4] = {};

#pragma unroll
  for (int ks = 0; ks < 4; ++ks) {
    short8 a[4], b[4];
#pragma unroll
    for (int m = 0; m < 4; ++m)
      a[m] = *(const short8*)(ap + (size_t)m * 16 * DD + ks * 32);
#pragma unroll
    for (int n = 0; n < 4; ++n)
      b[n] = *(const short8*)(bp + (size_t)n * 16 * DD + ks * 32);
#pragma unroll
    for (int m = 0; m < 4; ++m)
#pragma unroll
      for (int n = 0; n < 4; ++n)
        acc[m][n] = __builtin_amdgcn_mfma_f32_16x16x32_bf16(a[m], b[n], acc[m][n], 0, 0, 0);
  }

  // C/D layout (m89-verified): col = lane&15, row = (lane>>4)*4 + reg
  const int orow = (lane >> 4) * 4;
  const int ocol = lane & 15;
  float* op = out + (size_t)(row0 + orow) * MT + col0 + ocol;
#pragma unroll
  for (int m = 0; m < 4; ++m)
#pragma unroll
    for (int n = 0; n < 4; ++n)
#pragma unroll
      for (int j = 0; j < 4; ++j)
        op[(size_t)(m * 16 + j) * MT + n * 16] = acc[m][n][j];
}

extern "C" void kernel_launch(void* const* d_in, const int* in_sizes, int n_in,
                              void* d_out, int out_size, void* d_ws, size_t ws_size,
                              hipStream_t stream) {
  (void)in_sizes; (void)n_in; (void)out_size; (void)ws_size;
  const float* vis  = (const float*)d_in[0];  // [8192,128]
  const float* txt  = (const float*)d_in[1];  // [8192,768]
  const float* w    = (const float*)d_in[2];  // [128,768]
  const float* bias = (const float*)d_in[3];  // [128]
  float* out = (float*)d_out;                 // [8192,8192]

  // ws layout (bytes):
  //   vn  @ 0         : 8192*128 bf16 = 2 MB
  //   tn  @ 2 MB      : 8192*128 bf16 = 2 MB
  //   tb  @ 4 MB      : 8192*768 bf16 = 12 MB
  //   wb  @ 16 MB     : 128*768  bf16 = 192 KB
  //   tf  @ ~16.2 MB  : 8192*128 f32  = 4 MB
  char* ws = (char*)d_ws;
  ushort* vn = (ushort*)(ws);
  ushort* tn = (ushort*)(ws + (size_t)2097152);
  ushort* tb = (ushort*)(ws + (size_t)4194304);
  ushort* wb = (ushort*)(ws + (size_t)16777216);
  float*  tf = (float*) (ws + (size_t)16973824);

  k_visnorm<<<NV / 16, 256, 0, stream>>>(vis, vn);
  k_cvt<<<(MT * KB) / 2048, 256, 0, stream>>>(txt, tb);   // 3072 blocks
  k_cvt<<<(DD * KB) / 2048, 256, 0, stream>>>(w, wb);     // 48 blocks
  k_projmfma<<<dim3(2, MT / 64), 64, 0, stream>>>(tb, wb, tf);
  k_tnorm<<<MT / 16, 256, 0, stream>>>(tf, bias, tn);
  k_sim<<<dim3(MT / 128, NV / 128), 256, 0, stream>>>(vn, tn, out);
}